// Round 10
// baseline (156.045 us; speedup 1.0000x reference)
//
#include <hip/hip_runtime.h>
#include <cstdint>
#include <cstddef>

// Problem constants: W is [COUT, CIN]; x is [4*4096, CIN]. All I/O fp32.
#define CIN  1024
#define COUT 1024

typedef __attribute__((ext_vector_type(8))) short bf16x8;
typedef __attribute__((ext_vector_type(4))) float f32x4;

// ---------- fp32 -> bf16 (round-to-nearest-even) ----------
__device__ __forceinline__ unsigned short f2bf(float f) {
    union { float f; unsigned int i; } v;
    v.f = f;
    unsigned int u = v.i;
    u += 0x7FFFu + ((u >> 16) & 1u);
    return (unsigned short)(u >> 16);
}

__device__ __forceinline__ void cvt8(const float* __restrict__ s,
                                     unsigned short* __restrict__ d) {
    float4 v0 = *(const float4*)s;
    float4 v1 = *(const float4*)(s + 4);
    union { bf16x8 v; unsigned short u[8]; } w;
    w.u[0] = f2bf(v0.x); w.u[1] = f2bf(v0.y); w.u[2] = f2bf(v0.z); w.u[3] = f2bf(v0.w);
    w.u[4] = f2bf(v1.x); w.u[5] = f2bf(v1.y); w.u[6] = f2bf(v1.z); w.u[7] = f2bf(v1.w);
    *(bf16x8*)d = w.v;
}

// ---------- kernel 1: zero the fp32 W accumulation buffer ----------
__global__ void zero_f32(float4* __restrict__ p) {
    p[blockIdx.x * 256 + threadIdx.x] = float4{0.f, 0.f, 0.f, 0.f};
}

// ---------- kernel 2: fused {scatter-add into Wf} || {cvt x -> bf16} ----------
__global__ void scatter_cvtx(const float* __restrict__ vals,
                             const int* __restrict__ rows,
                             const int* __restrict__ cols,
                             float* __restrict__ W, int nnz, int nsb,
                             const float* __restrict__ x,
                             unsigned short* __restrict__ Xb) {
    const int b = blockIdx.x;
    if (b < nsb) {
        const int i = b * 256 + threadIdx.x;
        if (i < nnz) atomicAdd(W + (size_t)rows[i] * CIN + cols[i], vals[i]);
    } else {
        const size_t i = (((size_t)(b - nsb) * 256) + threadIdx.x) * 8;
        cvt8(x + i, Xb + i);
    }
}

// ---------- kernel 3: fp32 -> bf16 bulk convert (W) ----------
// Round-4 lesson: the x compression pass is NOT overhead (A-stream is shared;
// fusing the cvt into the GEMM doubled L3 traffic, +40us). Keep bf16 operands.
__global__ void cvt_bf16_bulk(const float* __restrict__ src, unsigned short* __restrict__ dst) {
    size_t i = ((size_t)blockIdx.x * 256 + threadIdx.x) * 8;
    cvt8(src + i, dst + i);
}

// ---------- kernel 4: 256x256 GEMM, v5 = barrier-free within a K-tile ----------
// C[M,N] = A[M,K](bf16) * B[N,K](bf16)^T -> fp32.
// v5 (single variable vs r8/r9): REMOVE the intra-tile quadrant barriers.
// Within a K-tile all 4 quadrant phases read the SAME buffer and stage into
// the OTHER one -> no data hazard between them; the per-phase barriers only
// chopped the LDS-read stream into bursts (LDS-port floor 15.4us vs 32us
// main loop = port idle half the time). New schedule, 2 barriers/K-tile:
//   tile t (buf = t&1):
//     [24 ds_read || 64 MFMA, compiler-interleaved, free-flowing]
//     s_barrier                  // every wave's MFMAs issued => reads retired
//     STAGE tile t+2 -> buf      // 8 gloads, fire-and-forget DMA
//     s_waitcnt vmcnt(8)         // completes S_{t+1} (issued one FULL tile
//                                // earlier, ~2000cyc cover) - counted, never
//                                // drains a same-instant stage (T4 at tile
//                                // granularity; avoids m230/m233's 2ph stall)
//     s_barrier                  // publish cross-wave
// Steady-state induction: at the vmcnt, outstanding = S_{t+1}(<=8) +
// S_{t+2}(8) -> waits exactly until S_{t+1} complete. Prologue: S_0,S_1;
// vmcnt(8) = S_0 done. t=14: no stage, vmcnt(0) drains S_15. t=15 = the
// r8-verified peel: per-quadrant C-stores after each final MFMA (64MB tail
// drains under remaining MFMA).
// All data maps r2/r8-verified: staging swizzle chunk^(row&7) on the global
// source (linear LDS dst), fragment chunk (ks*4+quad)^s7, C/D col=l16,
// row=quad*4+r.

#define GLD16(SRC_, DST_)                                                     \
  __builtin_amdgcn_global_load_lds(                                           \
      (const __attribute__((address_space(1))) void*)(SRC_),                  \
      (__attribute__((address_space(3))) void*)(DST_), 16, 0, 0)

#define STAGE_A(BUF_, HALF_, KT_) do {                                        \
    GLD16(pa + (size_t)((HALF_) * 128)      * CIN + (size_t)(KT_) * 64,       \
          As + (BUF_) * 16384 + ((HALF_) * 128) * 64 + tid8);                 \
    GLD16(pa + (size_t)((HALF_) * 128 + 64) * CIN + (size_t)(KT_) * 64,       \
          As + (BUF_) * 16384 + ((HALF_) * 128 + 64) * 64 + tid8);            \
  } while (0)

#define STAGE_B(BUF_, HALF_, KT_) do {                                        \
    GLD16(pb + (size_t)((HALF_) * 128)      * CIN + (size_t)(KT_) * 64,       \
          Bs + (BUF_) * 16384 + ((HALF_) * 128) * 64 + tid8);                 \
    GLD16(pb + (size_t)((HALF_) * 128 + 64) * CIN + (size_t)(KT_) * 64,       \
          Bs + (BUF_) * 16384 + ((HALF_) * 128 + 64) * 64 + tid8);            \
  } while (0)

// 8 gloads = one full 256x64 A-tile + 256x64 B-tile.
#define STAGE_TILE(BUF_, KT_) do {                                            \
    STAGE_A(BUF_, 0, KT_); STAGE_A(BUF_, 1, KT_);                             \
    STAGE_B(BUF_, 0, KT_); STAGE_B(BUF_, 1, KT_);                             \
  } while (0)

#define LOAD_A(BUF_, QA_) do {                                                \
    const unsigned short* ab_ = As + (BUF_) * 16384 + ((QA_) * 128 + wm64) * 64; \
    _Pragma("unroll")                                                         \
    for (int ks_ = 0; ks_ < 2; ++ks_) {                                       \
      const int cx_ = ((ks_ * 4 + quad) ^ s7) * 8;                            \
      _Pragma("unroll")                                                       \
      for (int mf_ = 0; mf_ < 4; ++mf_)                                       \
        af[ks_][mf_] = *(const bf16x8*)(ab_ + (mf_ * 16 + l16) * 64 + cx_);   \
    }                                                                         \
  } while (0)

#define LOAD_B(BUF_, QB_, DST_) do {                                          \
    const unsigned short* bb_ = Bs + (BUF_) * 16384 + ((QB_) * 128 + wn32) * 64; \
    _Pragma("unroll")                                                         \
    for (int ks_ = 0; ks_ < 2; ++ks_) {                                       \
      const int cx_ = ((ks_ * 4 + quad) ^ s7) * 8;                            \
      _Pragma("unroll")                                                       \
      for (int nf_ = 0; nf_ < 2; ++nf_)                                       \
        DST_[ks_][nf_] = *(const bf16x8*)(bb_ + (nf_ * 16 + l16) * 64 + cx_); \
    }                                                                         \
  } while (0)

#define MFMA_Q(QA_, QB_, BF_)                                                 \
    _Pragma("unroll")                                                         \
    for (int ks_ = 0; ks_ < 2; ++ks_)                                         \
      _Pragma("unroll")                                                       \
      for (int mf_ = 0; mf_ < 4; ++mf_)                                       \
        _Pragma("unroll")                                                     \
        for (int nf_ = 0; nf_ < 2; ++nf_)                                     \
          acc[QA_][QB_][mf_][nf_] = __builtin_amdgcn_mfma_f32_16x16x32_bf16(  \
              af[ks_][mf_], BF_[ks_][nf_], acc[QA_][QB_][mf_][nf_], 0, 0, 0)

// Whole K-tile, no internal barriers: reads flow under MFMA via compiler
// fine-grained lgkmcnt. Fragment persistence as v2 (af per-qa, bf whole tile).
#define TILE_COMPUTE(BUF_) do {                                               \
    bf16x8 af[2][4];                                                          \
    bf16x8 bf0[2][2], bf1[2][2];                                              \
    LOAD_A(BUF_, 0); LOAD_B(BUF_, 0, bf0); LOAD_B(BUF_, 1, bf1);              \
    __builtin_amdgcn_s_setprio(1);                                            \
    MFMA_Q(0, 0, bf0); MFMA_Q(0, 1, bf1);                                     \
    __builtin_amdgcn_s_setprio(0);                                            \
    LOAD_A(BUF_, 1);                                                          \
    __builtin_amdgcn_s_setprio(1);                                            \
    MFMA_Q(1, 0, bf0); MFMA_Q(1, 1, bf1);                                     \
    __builtin_amdgcn_s_setprio(0);                                            \
  } while (0)

#define WRITE_CQ(QA_, QB_) do {                                               \
    _Pragma("unroll")                                                         \
    for (int mf_ = 0; mf_ < 4; ++mf_)                                         \
      _Pragma("unroll")                                                       \
      for (int nf_ = 0; nf_ < 2; ++nf_) {                                     \
        const int row0_ = rowA0 + (QA_) * 128 + wm64 + mf_ * 16 + quad * 4;   \
        float* cp_ = C + (size_t)row0_ * COUT                                 \
                       + rowB0 + (QB_) * 128 + wn32 + nf_ * 16 + l16;         \
        _Pragma("unroll")                                                     \
        for (int r_ = 0; r_ < 4; ++r_)                                        \
            cp_[(size_t)r_ * COUT] = acc[QA_][QB_][mf_][nf_][r_];             \
      }                                                                       \
  } while (0)

__global__ __launch_bounds__(512, 2) void gemm_2bar(
    const unsigned short* __restrict__ A,   // [M, K] bf16
    const unsigned short* __restrict__ B,   // [N, K] bf16
    float* __restrict__ C,                  // [M, N] fp32
    int M) {
    (void)M;
    constexpr int K = CIN;

    __shared__ __align__(16) unsigned short As[2 * 16384];  // 2 x [256][64]
    __shared__ __align__(16) unsigned short Bs[2 * 16384];

    const int tid  = threadIdx.x;
    const int lane = tid & 63;
    const int w    = tid >> 6;
    const int quad = lane >> 4;
    const int l16  = lane & 15;
    const int s7   = l16 & 7;
    const int wm64 = (w >> 2) * 64;
    const int wn32 = (w & 3) * 32;

    const int rowA0 = blockIdx.x * 256;
    const int rowB0 = blockIdx.y * 256;

    const int stg_row = tid >> 3;
    const int c_data  = (tid & 7) ^ (stg_row & 7);
    const int tid8    = tid * 8;
    const unsigned short* pa = A + (size_t)(rowA0 + stg_row) * K + c_data * 8;
    const unsigned short* pb = B + (size_t)(rowB0 + stg_row) * K + c_data * 8;

    f32x4 acc[2][2][4][2] = {};

    // ---- prologue: tile0 -> buf0, tile1 -> buf1 ----
    STAGE_TILE(0, 0);
    STAGE_TILE(1, 1);
    asm volatile("s_waitcnt vmcnt(8)" ::: "memory");   // tile0 complete
    __builtin_amdgcn_s_barrier();

#pragma unroll 1
    for (int i = 0; i < 7; ++i) {          // tiles 0..13, 2 per iteration
        // tile 2i (buf0)
        TILE_COMPUTE(0);
        __builtin_amdgcn_s_barrier();                       // buf0 reads done
        STAGE_TILE(0, 2 * i + 2);
        asm volatile("s_waitcnt vmcnt(8)" ::: "memory");    // tile 2i+1 resident
        __builtin_amdgcn_s_barrier();
        // tile 2i+1 (buf1)
        TILE_COMPUTE(1);
        __builtin_amdgcn_s_barrier();                       // buf1 reads done
        STAGE_TILE(1, 2 * i + 3);
        asm volatile("s_waitcnt vmcnt(8)" ::: "memory");    // tile 2i+2 resident
        __builtin_amdgcn_s_barrier();
    }

    // ---- tile 14 (buf0): no further stages; drain S_15 ----
    TILE_COMPUTE(0);
    asm volatile("s_waitcnt vmcnt(0)" ::: "memory");        // tile 15 resident
    __builtin_amdgcn_s_barrier();

    // ---- tile 15 (buf1), peeled with per-quadrant C-stores ----
    {
        bf16x8 af[2][4];
        bf16x8 bf0[2][2], bf1[2][2];
        LOAD_A(1, 0); LOAD_B(1, 0, bf0); LOAD_B(1, 1, bf1);
        __builtin_amdgcn_s_setprio(1); MFMA_Q(0, 0, bf0); __builtin_amdgcn_s_setprio(0);
        WRITE_CQ(0, 0);

        __builtin_amdgcn_s_setprio(1); MFMA_Q(0, 1, bf1); __builtin_amdgcn_s_setprio(0);
        WRITE_CQ(0, 1);

        LOAD_A(1, 1);
        __builtin_amdgcn_s_setprio(1); MFMA_Q(1, 0, bf0); __builtin_amdgcn_s_setprio(0);
        WRITE_CQ(1, 0);

        __builtin_amdgcn_s_setprio(1); MFMA_Q(1, 1, bf1); __builtin_amdgcn_s_setprio(0);
        WRITE_CQ(1, 1);
    }
}

extern "C" void kernel_launch(void* const* d_in, const int* in_sizes, int n_in,
                              void* d_out, int out_size, void* d_ws, size_t ws_size,
                              hipStream_t stream) {
    const float* x    = (const float*)d_in[0];   // [M, CIN] fp32
    const float* vals = (const float*)d_in[1];   // [nnz] fp32
    const int*   idx  = (const int*)d_in[2];     // [2, nnz] int32

    float* out = (float*)d_out;                  // [M, COUT] fp32

    const int nnz = in_sizes[2] / 2;
    const int M   = in_sizes[0] / CIN;

    const size_t wf_bytes = (size_t)COUT * CIN * sizeof(float);          // 4 MB
    const size_t wb_bytes = (size_t)COUT * CIN * sizeof(unsigned short); // 2 MB

    float*          Wf = (float*)d_ws;
    unsigned short* Wb = (unsigned short*)((char*)d_ws + wf_bytes);
    unsigned short* Xb = (unsigned short*)((char*)d_ws + wf_bytes + wb_bytes);

    const int nsb = (nnz + 255) / 256;                                    // 512
    const unsigned cvtx_blocks = (unsigned)((size_t)M * CIN / (256 * 8)); // 8192

    // 1) zero fp32 W (ws is poisoned 0xAA before every call)
    zero_f32<<<dim3(COUT * CIN / (256 * 4)), dim3(256), 0, stream>>>((float4*)Wf);
    // 2) scatter-add (needs zeroed W) || x -> bf16 (independent) in one launch
    scatter_cvtx<<<dim3((unsigned)nsb + cvtx_blocks), dim3(256), 0, stream>>>(
        vals, idx, idx + nnz, Wf, nnz, nsb, x, Xb);
    // 3) W -> bf16
    cvt_bf16_bulk<<<dim3(COUT * CIN / (256 * 8)), dim3(256), 0, stream>>>(Wf, Wb);
    // 4) GEMM, 2 barriers/K-tile, free-flowing intra-tile reads + peeled tail.
    gemm_2bar<<<dim3(M / 256, COUT / 256), dim3(512), 0, stream>>>(Xb, Wb, out, M);
}